// Round 6
// baseline (3997.426 us; speedup 1.0000x reference)
//
#include <hip/hip_runtime.h>
#include <math.h>

#define NTHR 1024

constexpr int EG_STRIDE = 16384;   // floats per batch: e1 only (128 rows x 128)

__device__ __forceinline__ int xoff(int l) { return 512 - (512 >> l); }   // l in 0..7

// ---- MLP chunk, C rows (levels 0 and 4): R3-proven register shape ----
// layer1: 16 waves = 8 kg (32k) x 2 col-halves, 2 cols/lane; 8 iters x 4
// float2 weights (8 regs). layer2: 16 kg (16k); 4 iters x 4 float2.
// `#pragma unroll 1` on k-loops is load-bearing (R1/R2: full unroll ->
// scheduler hoists loads past the 64-VGPR cap -> 21 GB scratch spill).
template <int C>
__device__ __forceinline__ void mlp_chunk(
    const float* zl, int zstr,
    const float* __restrict__ W1, const float* __restrict__ B1,
    const float* __restrict__ W2, const float* __restrict__ B2,
    const float* lab, bool uselab, const int* u1h, int done,
    float* red, float* h, float* eout)
{
  const int t  = threadIdx.x;
  const int wv = t >> 6;
  const int ln = t & 63;
  // ---------- layer 1 ----------
  {
    const int kg = wv >> 1;
    const int c1 = (wv & 1) * 128 + 2 * ln;
    const float* wb = W1 + 32 * kg * 256 + c1;
    const float* zb = zl + 32 * kg;
    float2 acc[C];
#pragma unroll
    for (int r = 0; r < C; ++r) acc[r] = make_float2(0.f, 0.f);
#pragma unroll 1
    for (int blk = 0; blk < 8; ++blk) {
      const float* wp = wb + 4 * blk * 256;
      const float2 w0 = *reinterpret_cast<const float2*>(wp);
      const float2 w1 = *reinterpret_cast<const float2*>(wp + 256);
      const float2 w2 = *reinterpret_cast<const float2*>(wp + 512);
      const float2 w3 = *reinterpret_cast<const float2*>(wp + 768);
#pragma unroll
      for (int r = 0; r < C; ++r) {
        const float4 z = *reinterpret_cast<const float4*>(zb + r * zstr + 4 * blk);
        acc[r].x = fmaf(z.x,w0.x, fmaf(z.y,w1.x, fmaf(z.z,w2.x, fmaf(z.w,w3.x, acc[r].x))));
        acc[r].y = fmaf(z.x,w0.y, fmaf(z.y,w1.y, fmaf(z.z,w2.y, fmaf(z.w,w3.y, acc[r].y))));
      }
    }
#pragma unroll
    for (int r = 0; r < C; ++r)
      *reinterpret_cast<float2*>(red + (kg * C + r) * 256 + c1) = acc[r];
  }
  __syncthreads();
  // ---------- reduce1 + bias (+lab) + relu -> h ----------
  if (t < 128 * C) {
    const int r  = t >> 7;
    const int c0 = 2 * (t & 127);
    float2 s = *reinterpret_cast<const float2*>(B1 + c0);
    if (uselab) {
      const int j = u1h[done + r] & 1;
      const float2 lv = *reinterpret_cast<const float2*>(lab + j * 256 + c0);
      s.x += lv.x; s.y += lv.y;
    }
#pragma unroll
    for (int q = 0; q < 8; ++q) {
      const float2 p = *reinterpret_cast<const float2*>(red + (q * C + r) * 256 + c0);
      s.x += p.x; s.y += p.y;
    }
    s.x = fmaxf(s.x, 0.f); s.y = fmaxf(s.y, 0.f);
    *reinterpret_cast<float2*>(h + r * 256 + c0) = s;
  }
  __syncthreads();
  // ---------- layer 2 ----------
  {
    const int c2 = 2 * ln;
    float2 acc[C];
#pragma unroll
    for (int r = 0; r < C; ++r) acc[r] = make_float2(0.f, 0.f);
#pragma unroll 1
    for (int blk = 0; blk < 4; ++blk) {
      const float* wp = W2 + (16 * wv + 4 * blk) * 128 + c2;
      const float2 w0 = *reinterpret_cast<const float2*>(wp);
      const float2 w1 = *reinterpret_cast<const float2*>(wp + 128);
      const float2 w2 = *reinterpret_cast<const float2*>(wp + 256);
      const float2 w3 = *reinterpret_cast<const float2*>(wp + 384);
#pragma unroll
      for (int r = 0; r < C; ++r) {
        const float4 hv = *reinterpret_cast<const float4*>(h + r * 256 + 16 * wv + 4 * blk);
        acc[r].x = fmaf(hv.x,w0.x, fmaf(hv.y,w1.x, fmaf(hv.z,w2.x, fmaf(hv.w,w3.x, acc[r].x))));
        acc[r].y = fmaf(hv.x,w0.y, fmaf(hv.y,w1.y, fmaf(hv.z,w2.y, fmaf(hv.w,w3.y, acc[r].y))));
      }
    }
#pragma unroll
    for (int r = 0; r < C; ++r)
      *reinterpret_cast<float2*>(red + (wv * C + r) * 128 + c2) = acc[r];
  }
  __syncthreads();
  // ---------- reduce2 + bias -> eout ----------
  if (t < 64 * C) {
    const int r  = t >> 6;
    const int c0 = 2 * (t & 63);
    float2 s = *reinterpret_cast<const float2*>(B2 + c0);
#pragma unroll
    for (int q = 0; q < 16; ++q) {
      const float2 p = *reinterpret_cast<const float2*>(red + (q * C + r) * 128 + c0);
      s.x += p.x; s.y += p.y;
    }
    *reinterpret_cast<float2*>(eout + r * 128 + c0) = s;
  }
  __syncthreads();
}

// ---- 16-row MLP chunk (levels 1..3): halves chunk count of the heavy
// levels, amortizing per-phase overhead over 2x FMAs. Register shape mirrors
// the proven R3 chunk: 8 scalar weight regs per serial iter, acc[16].
// layer1: 16 waves = 4 kg (64k) x 4 col-quarters (1 col/lane); red = 4x16x256
// = 16384 exactly. layer2: 8 kg (32k) x 2 col-halves; red = 8x16x128.
__device__ __forceinline__ void mlp_chunk16(
    const float* zl,
    const float* __restrict__ W1, const float* __restrict__ B1,
    const float* __restrict__ W2, const float* __restrict__ B2,
    const float* lab, bool uselab, const int* u1h, int done,
    float* red, float* h, float* eout)
{
  const int t  = threadIdx.x;
  const int wv = t >> 6;
  const int ln = t & 63;
  // ---------- layer 1 ----------
  {
    const int kg = wv >> 2;                       // 0..3, 64 k each
    const int c1 = (wv & 3) * 64 + ln;            // 1 col/lane
    const float* wb = W1 + 64 * kg * 256 + c1;
    const float* zb = zl + 64 * kg;
    float acc[16];
#pragma unroll
    for (int r = 0; r < 16; ++r) acc[r] = 0.f;
#pragma unroll 1
    for (int it = 0; it < 8; ++it) {              // 8 k per iter, 8 scalar w
      const float* wp = wb + 8 * it * 256;
      const float w0 = wp[0],        w1 = wp[256],  w2 = wp[512],  w3 = wp[768];
      const float w4 = wp[1024],     w5 = wp[1280], w6 = wp[1536], w7 = wp[1792];
#pragma unroll
      for (int r = 0; r < 16; ++r) {
        const float* zr = zb + r * 256 + 8 * it;
        const float4 za = *reinterpret_cast<const float4*>(zr);
        const float4 zc = *reinterpret_cast<const float4*>(zr + 4);
        acc[r] = fmaf(za.x,w0, fmaf(za.y,w1, fmaf(za.z,w2, fmaf(za.w,w3, acc[r]))));
        acc[r] = fmaf(zc.x,w4, fmaf(zc.y,w5, fmaf(zc.z,w6, fmaf(zc.w,w7, acc[r]))));
      }
    }
#pragma unroll
    for (int r = 0; r < 16; ++r)
      red[(kg * 16 + r) * 256 + c1] = acc[r];
  }
  __syncthreads();
  // ---------- reduce1 + bias (+lab) + relu -> h ----------
  for (int idx = t; idx < 2048; idx += NTHR) {
    const int r  = idx >> 7;
    const int c0 = 2 * (idx & 127);
    float2 s = *reinterpret_cast<const float2*>(B1 + c0);
    if (uselab) {
      const int j = u1h[done + r] & 1;
      const float2 lv = *reinterpret_cast<const float2*>(lab + j * 256 + c0);
      s.x += lv.x; s.y += lv.y;
    }
#pragma unroll
    for (int q = 0; q < 4; ++q) {
      const float* rp = red + (q * 16 + r) * 256 + c0;
      s.x += rp[0]; s.y += rp[1];
    }
    s.x = fmaxf(s.x, 0.f); s.y = fmaxf(s.y, 0.f);
    *reinterpret_cast<float2*>(h + r * 256 + c0) = s;
  }
  __syncthreads();
  // ---------- layer 2 ----------
  {
    const int kg = wv >> 1;                       // 0..7, 32 k each
    const int c2 = (wv & 1) * 64 + ln;
    const float* wb2 = W2 + 32 * kg * 128 + c2;
    const float* hb = h + 32 * kg;
    float acc[16];
#pragma unroll
    for (int r = 0; r < 16; ++r) acc[r] = 0.f;
#pragma unroll 1
    for (int it = 0; it < 4; ++it) {              // 8 k per iter
      const float* wp = wb2 + 8 * it * 128;
      const float w0 = wp[0],   w1 = wp[128], w2 = wp[256], w3 = wp[384];
      const float w4 = wp[512], w5 = wp[640], w6 = wp[768], w7 = wp[896];
#pragma unroll
      for (int r = 0; r < 16; ++r) {
        const float* hr = hb + r * 256 + 8 * it;
        const float4 ha = *reinterpret_cast<const float4*>(hr);
        const float4 hc = *reinterpret_cast<const float4*>(hr + 4);
        acc[r] = fmaf(ha.x,w0, fmaf(ha.y,w1, fmaf(ha.z,w2, fmaf(ha.w,w3, acc[r]))));
        acc[r] = fmaf(hc.x,w4, fmaf(hc.y,w5, fmaf(hc.z,w6, fmaf(hc.w,w7, acc[r]))));
      }
    }
#pragma unroll
    for (int r = 0; r < 16; ++r)
      red[(kg * 16 + r) * 128 + c2] = acc[r];
  }
  __syncthreads();
  // ---------- reduce2 + bias -> eout ----------
  for (int idx = t; idx < 2048; idx += NTHR) {
    const int r = idx >> 7;
    const int c = idx & 127;
    float s = B2[c];
#pragma unroll
    for (int q = 0; q < 8; ++q) s += red[(q * 16 + r) * 128 + c];
    eout[r * 128 + c] = s;
  }
  __syncthreads();
}

// ---- fused check+speculative-bit chunk for deep levels (l in {5,6,7}) ----
// layer1: 2R partial rows (check + bit, label enters only as bias); reduce1:
// 3R h rows (check | bit+lab0 | bit+lab1); layer2 split-K 8: 3R rows;
// reduce2: check -> eout, bit -> spec[2][R][128]. Bit-time collapses to a
// select (l=5,6) or feeds leaves directly (l=7).
template <int R>
__device__ __forceinline__ void fused_chunk(
    const float* zl,
    const float* __restrict__ Wc1_, const float* __restrict__ Bc1_,
    const float* __restrict__ Wc2_, const float* __restrict__ Bc2_,
    const float* __restrict__ Wb1_, const float* __restrict__ Bb1_,
    const float* __restrict__ Wb2_, const float* __restrict__ Bb2_,
    const float* lab,
    float* red, float* h, float* eout, float* spec)
{
  const int t  = threadIdx.x;
  const int wv = t >> 6;
  const int ln = t & 63;
  // ---------- layer 1: 8 kg x 2 col-halves; 2R partial rows ----------
  {
    const int kg = wv >> 1;
    const int c1 = (wv & 1) * 128 + 2 * ln;
    const float* wcb = Wc1_ + 32 * kg * 256 + c1;
    const float* wbb = Wb1_ + 32 * kg * 256 + c1;
    const float* zb  = zl + 32 * kg;
    float2 ac[R], ab[R];
#pragma unroll
    for (int r = 0; r < R; ++r) { ac[r] = make_float2(0.f,0.f); ab[r] = make_float2(0.f,0.f); }
#pragma unroll 1
    for (int blk = 0; blk < 8; ++blk) {
      const float* wcp = wcb + 4 * blk * 256;
      const float* wbp = wbb + 4 * blk * 256;
      const float2 c0 = *reinterpret_cast<const float2*>(wcp);
      const float2 c1v = *reinterpret_cast<const float2*>(wcp + 256);
      const float2 c2v = *reinterpret_cast<const float2*>(wcp + 512);
      const float2 c3v = *reinterpret_cast<const float2*>(wcp + 768);
      const float2 b0 = *reinterpret_cast<const float2*>(wbp);
      const float2 b1 = *reinterpret_cast<const float2*>(wbp + 256);
      const float2 b2 = *reinterpret_cast<const float2*>(wbp + 512);
      const float2 b3 = *reinterpret_cast<const float2*>(wbp + 768);
      float4 z[R];
#pragma unroll
      for (int r = 0; r < R; ++r)
        z[r] = *reinterpret_cast<const float4*>(zb + r * 256 + 4 * blk);
#pragma unroll
      for (int r = 0; r < R; ++r) {
        ac[r].x = fmaf(z[r].x,c0.x, fmaf(z[r].y,c1v.x, fmaf(z[r].z,c2v.x, fmaf(z[r].w,c3v.x, ac[r].x))));
        ac[r].y = fmaf(z[r].x,c0.y, fmaf(z[r].y,c1v.y, fmaf(z[r].z,c2v.y, fmaf(z[r].w,c3v.y, ac[r].y))));
        ab[r].x = fmaf(z[r].x,b0.x, fmaf(z[r].y,b1.x, fmaf(z[r].z,b2.x, fmaf(z[r].w,b3.x, ab[r].x))));
        ab[r].y = fmaf(z[r].x,b0.y, fmaf(z[r].y,b1.y, fmaf(z[r].z,b2.y, fmaf(z[r].w,b3.y, ab[r].y))));
      }
    }
#pragma unroll
    for (int r = 0; r < R; ++r) {
      *reinterpret_cast<float2*>(red + (kg * 2 * R + r) * 256 + c1) = ac[r];
      *reinterpret_cast<float2*>(red + (kg * 2 * R + R + r) * 256 + c1) = ab[r];
    }
  }
  __syncthreads();
  // ---------- reduce1 -> h: 3R rows ----------
  for (int idx = t; idx < 3 * R * 128; idx += NTHR) {
    const int r  = idx >> 7;
    const int c0 = 2 * (idx & 127);
    const int pr = (r < 2 * R) ? r : r - R;     // bit partials shared by variants
    float2 s;
    if (r < R) {
      s = *reinterpret_cast<const float2*>(Bc1_ + c0);
    } else {
      s = *reinterpret_cast<const float2*>(Bb1_ + c0);
      const float2 lv = *reinterpret_cast<const float2*>(lab + ((r < 2 * R) ? 0 : 256) + c0);
      s.x += lv.x; s.y += lv.y;
    }
#pragma unroll
    for (int q = 0; q < 8; ++q) {
      const float2 p = *reinterpret_cast<const float2*>(red + (q * 2 * R + pr) * 256 + c0);
      s.x += p.x; s.y += p.y;
    }
    s.x = fmaxf(s.x, 0.f); s.y = fmaxf(s.y, 0.f);
    *reinterpret_cast<float2*>(h + r * 256 + c0) = s;
  }
  __syncthreads();
  // ---------- layer 2: 8 kg x 2 col-halves (1 col/lane); 3R rows ----------
  {
    const int kg = wv >> 1;
    const int c2 = (wv & 1) * 64 + ln;
    const float* wcb = Wc2_ + 32 * kg * 128 + c2;
    const float* wbb = Wb2_ + 32 * kg * 128 + c2;
    float acc[3 * R];
#pragma unroll
    for (int r = 0; r < 3 * R; ++r) acc[r] = 0.f;
#pragma unroll 1
    for (int blk = 0; blk < 8; ++blk) {
      const float* wcp = wcb + 4 * blk * 128;
      const float* wbp = wbb + 4 * blk * 128;
      const float c0v = wcp[0], c1v = wcp[128], c2v = wcp[256], c3v = wcp[384];
      const float b0v = wbp[0], b1v = wbp[128], b2v = wbp[256], b3v = wbp[384];
      const float* hb = h + 32 * kg + 4 * blk;
#pragma unroll
      for (int r = 0; r < 3 * R; ++r) {
        const float4 hv = *reinterpret_cast<const float4*>(hb + r * 256);
        if (r < R)
          acc[r] = fmaf(hv.x,c0v, fmaf(hv.y,c1v, fmaf(hv.z,c2v, fmaf(hv.w,c3v, acc[r]))));
        else
          acc[r] = fmaf(hv.x,b0v, fmaf(hv.y,b1v, fmaf(hv.z,b2v, fmaf(hv.w,b3v, acc[r]))));
      }
    }
#pragma unroll
    for (int r = 0; r < 3 * R; ++r)
      red[(kg * 3 * R + r) * 128 + c2] = acc[r];
  }
  __syncthreads();
  // ---------- reduce2: check -> eout, bit -> spec[2][R][128] ----------
  for (int idx = t; idx < 3 * R * 128; idx += NTHR) {
    const int r = idx >> 7;
    const int c = idx & 127;
    float s = (r < R) ? Bc2_[c] : Bb2_[c];
#pragma unroll
    for (int q = 0; q < 8; ++q) s += red[(q * 3 * R + r) * 128 + c];
    if (r < R)            eout[r * 128 + c] = s;
    else if (r < 2 * R)   spec[(r - R) * 128 + c] = s;
    else                  spec[R * 128 + (r - 2 * R) * 128 + c] = s;
  }
  __syncthreads();
}

__global__ void sc_setup(const int* __restrict__ info_set,
                         const float* __restrict__ E_obs,
                         const float* __restrict__ E_lab,
                         const float* __restrict__ Wb1,
                         int* __restrict__ pos2k, float* __restrict__ lab1,
                         float* __restrict__ eroot)
{
  const int t = threadIdx.x;   // 256 threads
  pos2k[t] = -1;
  __syncthreads();
  if (t < 128) pos2k[info_set[t]] = t;
  eroot[t] = E_obs[2 * 128 + (t & 127)];
  for (int j = 0; j < 2; ++j) {
    float s = 0.0f;
    for (int k = 0; k < 128; ++k)
      s = fmaf(E_lab[j * 128 + k], Wb1[(256 + k) * 256 + t], s);
    lab1[j * 256 + t] = s;
  }
}

__global__ __launch_bounds__(NTHR)
__attribute__((amdgpu_waves_per_eu(4, 4)))
void sc_main(const int* __restrict__ info_bits, const float* __restrict__ rin,
             const float* __restrict__ Wc1, const float* __restrict__ bc1,
             const float* __restrict__ Wc2, const float* __restrict__ bc2,
             const float* __restrict__ Wb1, const float* __restrict__ bb1,
             const float* __restrict__ Wb2, const float* __restrict__ bb2,
             const float* __restrict__ Wl, const float* __restrict__ bl,
             const int* __restrict__ pos2k, const float* __restrict__ lab1_g,
             const float* __restrict__ eroot_g,
             float* __restrict__ wsall, float* __restrict__ out)
{
  const int b = blockIdx.x;
  const int t = threadIdx.x;
  float* e1g = wsall + (size_t)b * EG_STRIDE;      // level-1 e (global)

  __shared__ __align__(16) float red[16384];       // 64 KB split-K partials
  __shared__ __align__(16) float h_lds[4096];      // 16 KB hidden / lvl-1 z-stage
  __shared__ __align__(16) float scratch[1792];    //  7 KB: lvl-0 out UNION specs
                                                   //  spec5[0,1024) spec6[1024,1536) spec7[1536,1792)
  __shared__ __align__(16) float e2[8192];         // 32 KB level-2 e
  __shared__ __align__(16) float e3[4096];         // 16 KB level-3 e
  __shared__ __align__(16) float e4[2048];         //  8 KB level-4 e
  __shared__ __align__(16) float e5678[1920];      // levels 5..8: 8,4,2,1 rows
  __shared__ __align__(16) float lab_lds[512];
  __shared__ __align__(16) float eroot[256];
  __shared__ float rrow[256];
  __shared__ float wl_lds[132];                    // Wl[128] + bl at [128]
  __shared__ float dots[4];                        // e8 / spec7[0] / spec7[1] LLR dots
  __shared__ int   xh[520];
  __shared__ int   ibits[128];
  __shared__ int   p2k_l[256];

  float* xO = out;
  float* fO = out + 32768;
  float* uO = out + 65536;
  float* pO = out + 98304;
  float* rO = out + 131072;

  // ---- prologue: preload constants, hoist input-independent outputs ----
  if (t < 512) lab_lds[t] = lab1_g[t];
  if (t < 256) {
    eroot[t]  = eroot_g[t];
    const int k = pos2k[t];
    p2k_l[t]  = k;
    const float rv = rin[b * 256 + t];
    rrow[t]   = rv;
    rO[b * 256 + t] = rv;
    fO[b * 256 + t] = (k >= 0) ? 2.0f : 1.0f;
  }
  if (t < 128) { ibits[t] = info_bits[b * 128 + t]; wl_lds[t] = Wl[t]; }
  if (t == 128) wl_lds[128] = bl[0];
  if (t == 0) { xh[512] = 0; xh[513] = 1; }        // constant u1h for lvl-0 bit
  __syncthreads();

  // ---- levels 1..4 (C16 for 1..3, C8 for 4) ----
  auto run_level = [&](int l, bool isbit) {
    const float* W1 = isbit ? Wb1 : Wc1;
    const float* B1 = isbit ? bb1 : bc1;
    const float* W2 = isbit ? Wb2 : Wc2;
    const float* B2 = isbit ? bb2 : bc2;
    const int* u1h = xh + xoff(l);
    if (l <= 3) {
      const int rows = 128 >> l;                   // 64 / 32 / 16
      const float* ein = (l == 2) ? e2 : (l == 3) ? e3 : nullptr;
      float* eo = (l == 1) ? e2 : (l == 2) ? e3 : e4;
      for (int done = 0; done < rows; done += 16) {
        const float* zl;
        if (l == 1) {   // stage 16 z-rows (4096 floats) into h_lds (dead here)
          const float4* src = reinterpret_cast<const float4*>(e1g + done * 256);
          for (int i4 = t; i4 < 1024; i4 += NTHR)
            reinterpret_cast<float4*>(h_lds)[i4] = src[i4];
          __syncthreads();
          zl = h_lds;
        } else {
          zl = ein + done * 256;
        }
        mlp_chunk16(zl, W1, B1, W2, B2, lab_lds, isbit, u1h, done,
                    red, h_lds, eo + done * 128);
      }
    } else {           // l == 4: one C8 chunk
      mlp_chunk<8>(e4, 256, W1, B1, W2, B2, lab_lds, isbit, u1h, 0,
                   red, h_lds, e5678);
    }
  };

  // ---- level 0 special: check rows all identical (z = eroot); bit rows take
  // only 2 values. Compute 1 (check) or 2 (bit) rows, broadcast into e1. ----
  auto run_level0 = [&](bool isbit) {
    if (!isbit) {
      mlp_chunk<1>(eroot, 0, Wc1, bc1, Wc2, bc2, lab_lds, false, xh, 0, red, h_lds, scratch);
      for (int i4 = t; i4 < 4096; i4 += NTHR)
        reinterpret_cast<float4*>(e1g)[i4] =
            reinterpret_cast<const float4*>(scratch)[i4 & 31];
    } else {
      mlp_chunk<2>(eroot, 0, Wb1, bb1, Wb2, bb2, lab_lds, true, xh + 512, 0, red, h_lds, scratch);
      for (int i4 = t; i4 < 4096; i4 += NTHR)
        reinterpret_cast<float4*>(e1g)[i4] =
            reinterpret_cast<const float4*>(scratch)[(xh[i4 >> 5] & 1) * 32 + (i4 & 31)];
    }
    __syncthreads();
  };

  // ---- fused check+spec for l in {5,6,7} ----
  auto run_fused = [&](int l) {
    if (l == 5)
      fused_chunk<4>(e5678, Wc1, bc1, Wc2, bc2, Wb1, bb1, Wb2, bb2, lab_lds,
                     red, h_lds, e5678 + 1024, scratch);
    else if (l == 6)
      fused_chunk<2>(e5678 + 1024, Wc1, bc1, Wc2, bc2, Wb1, bb1, Wb2, bb2, lab_lds,
                     red, h_lds, e5678 + 1536, scratch + 1024);
    else
      fused_chunk<1>(e5678 + 1536, Wc1, bc1, Wc2, bc2, Wb1, bb1, Wb2, bb2, lab_lds,
                     red, h_lds, e5678 + 1792, scratch + 1536);
  };

  // ---- bit-time select for l in {5,6}: child e row r = spec[u1h[r]][r] ----
  auto do_select = [&](int l) {
    const int R = 128 >> l;
    const float* spec = scratch + ((l == 5) ? 0 : 1024);
    float* eo = (l == 5) ? (e5678 + 1024) : (e5678 + 1536);
    const int* u1h = xh + xoff(l);
    if (t < R * 128) {
      const int r = t >> 7;
      eo[t] = spec[(u1h[r] & 1) * R * 128 + t];
    }
    __syncthreads();
  };

  // ---- leaf pair: one parallel dot phase (3 waves), one scalar decide ----
  auto do_dots = [&]() {
    if (t < 192) {
      const int g = t >> 6, l6 = t & 63;
      const float* row = (g == 0) ? (e5678 + 1792) : (scratch + 1536 + (g - 1) * 128);
      float partial = row[l6] * wl_lds[l6] + row[l6 + 64] * wl_lds[l6 + 64];
#pragma unroll
      for (int m = 32; m >= 1; m >>= 1) partial += __shfl_xor(partial, m);
      if (l6 == 0) dots[g] = partial + wl_lds[128];
    }
    __syncthreads();
  };
  auto do_decide = [&](int i, int s) {   // i even; s = ctz(i+2)
    if (t == 0) {
      int xv[2];
#pragma unroll
      for (int q = 0; q < 2; ++q) {
        const float dv = (q == 0) ? dots[0] : dots[1 + (xv[0] & 1)];
        const float p  = 1.0f / (1.0f + expf(-dv));
        const float rv = rrow[i + q];
        const int  hd     = (rv > p) ? 1 : 0;
        const bool frozen = fabsf(p - 0.5f) > 0.25f;
        const int  k  = p2k_l[i + q];
        const int  fc = (k >= 0) ? ibits[k] : 2;
        xv[q] = (fc == 2 || frozen) ? hd : fc;
        pO[b * 256 + i + q] = p;
        uO[b * 256 + i + q] = (float)xv[q];
      }
      const int side = (1 < s) ? 1 : 0;            // combine j=1 (level 7)
      const int base = xoff(6) + side * 2;
      xh[base]     = xv[0] ^ xv[1];
      xh[base + 1] = xv[1];
    }
    __syncthreads();
  };

  auto do_combine = [&](int l, int side) {
    const int n = 256 >> l, half = n >> 1;
    if (t < half) {
      const int u1 = xh[xoff(l) + t];
      const int u2 = xh[xoff(l) + half + t];
      if (l > 0) {
        const int base = xoff(l - 1) + side * n;
        xh[base + 2 * t]     = u1 ^ u2;
        xh[base + 2 * t + 1] = u2;
      } else {
        xO[b * 256 + 2 * t]     = (float)(u1 ^ u2);
        xO[b * 256 + 2 * t + 1] = (float)u2;
      }
    }
    __syncthreads();
  };

  // ---- SC traversal ----
  int i = 0, l = 0;
  bool isbit = false;
  while (true) {
    if (l >= 5) {
      if (isbit) do_select(l);           // l is 5 or 6 here
      else       run_fused(l);
    } else if (l == 0) {
      run_level0(isbit);
    } else {
      run_level(l, isbit);
    }
    if (l < 7) { ++l; isbit = false; continue; }
    // l == 7 check: f7 just ran -> leaves i, i+1
    do_dots();
    const int s = __builtin_ctz(i + 2);
    do_decide(i, s);
    if (i == 254) {
      for (int j = 2; j <= 8; ++j) do_combine(8 - j, (j < s) ? 1 : 0);
      break;
    }
    i += 2;
    for (int j = 2; j <= s; ++j) do_combine(8 - j, (j < s) ? 1 : 0);
    l = 7 - s;
    isbit = true;
  }
}

extern "C" void kernel_launch(void* const* d_in, const int* in_sizes, int n_in,
                              void* d_out, int out_size, void* d_ws, size_t ws_size,
                              hipStream_t stream)
{
  const int*   info_bits = (const int*)  d_in[0];
  const float* rin       = (const float*)d_in[1];
  const int*   info_set  = (const int*)  d_in[2];
  const float* E_obs     = (const float*)d_in[3];
  const float* E_lab     = (const float*)d_in[4];
  const float* Wc1 = (const float*)d_in[5];
  const float* bc1 = (const float*)d_in[6];
  const float* Wc2 = (const float*)d_in[7];
  const float* bc2 = (const float*)d_in[8];
  const float* Wb1 = (const float*)d_in[9];
  const float* bb1 = (const float*)d_in[10];
  const float* Wb2 = (const float*)d_in[11];
  const float* bb2 = (const float*)d_in[12];
  const float* Wl  = (const float*)d_in[13];
  const float* bl  = (const float*)d_in[14];

  int*   pos2k = (int*)d_ws;                 // 256 ints
  float* lab1  = (float*)d_ws + 256;         // 512 floats
  float* eroot = (float*)d_ws + 768;         // 256 floats
  float* wsall = (float*)d_ws + 1024;        // 128 x EG_STRIDE floats

  hipLaunchKernelGGL(sc_setup, dim3(1), dim3(256), 0, stream,
                     info_set, E_obs, E_lab, Wb1, pos2k, lab1, eroot);
  hipLaunchKernelGGL(sc_main, dim3(128), dim3(NTHR), 0, stream,
                     info_bits, rin,
                     Wc1, bc1, Wc2, bc2, Wb1, bb1, Wb2, bb2, Wl, bl,
                     pos2k, lab1, eroot, wsall, (float*)d_out);
}

// Round 7
// 3744.829 us; speedup vs baseline: 1.0675x; 1.0675x over previous
//
#include <hip/hip_runtime.h>
#include <math.h>

#define NTHR 1024

constexpr int EG_STRIDE = 16384;   // floats per batch: e1 only (128 rows x 128)

__device__ __forceinline__ int xoff(int l) { return 512 - (512 >> l); }   // l in 0..7

// ---- MLP chunk, C rows: R3-proven register shape + depth-1 weight prefetch.
// layer1: 16 waves = 8 kg (32k) x 2 col-halves, 2 cols/lane. layer2: 16 kg.
// `#pragma unroll 1` on k-loops is load-bearing (R1/R2: full unroll ->
// scheduler hoists loads past the 64-VGPR cap -> 21 GB scratch spill).
// Prefetch: next iteration's 4 float2 weights issue at the TOP of the body
// (+8 VGPRs only — R4's failure was bundling a 32-reg z-batch on top), so the
// serial chain per iter is FMA-issue, not L2 latency.
template <int C>
__device__ __forceinline__ void mlp_chunk(
    const float* zl, int zstr,
    const float* __restrict__ W1, const float* __restrict__ B1,
    const float* __restrict__ W2, const float* __restrict__ B2,
    const float* lab, bool uselab, const int* u1h, int done,
    float* red, float* h, float* eout)
{
  const int t  = threadIdx.x;
  const int wv = t >> 6;
  const int ln = t & 63;
  // ---------- layer 1 ----------
  {
    const int kg = wv >> 1;
    const int c1 = (wv & 1) * 128 + 2 * ln;
    const float* wb = W1 + 32 * kg * 256 + c1;
    const float* zb = zl + 32 * kg;
    float2 acc[C];
#pragma unroll
    for (int r = 0; r < C; ++r) acc[r] = make_float2(0.f, 0.f);
    float2 w0 = *reinterpret_cast<const float2*>(wb);
    float2 w1 = *reinterpret_cast<const float2*>(wb + 256);
    float2 w2 = *reinterpret_cast<const float2*>(wb + 512);
    float2 w3 = *reinterpret_cast<const float2*>(wb + 768);
#pragma unroll 1
    for (int blk = 0; blk < 8; ++blk) {
      const float* wn = wb + 4 * ((blk < 7) ? blk + 1 : 7) * 256;
      const float2 n0 = *reinterpret_cast<const float2*>(wn);
      const float2 n1 = *reinterpret_cast<const float2*>(wn + 256);
      const float2 n2 = *reinterpret_cast<const float2*>(wn + 512);
      const float2 n3 = *reinterpret_cast<const float2*>(wn + 768);
#pragma unroll
      for (int r = 0; r < C; ++r) {
        const float4 z = *reinterpret_cast<const float4*>(zb + r * zstr + 4 * blk);
        acc[r].x = fmaf(z.x,w0.x, fmaf(z.y,w1.x, fmaf(z.z,w2.x, fmaf(z.w,w3.x, acc[r].x))));
        acc[r].y = fmaf(z.x,w0.y, fmaf(z.y,w1.y, fmaf(z.z,w2.y, fmaf(z.w,w3.y, acc[r].y))));
      }
      w0 = n0; w1 = n1; w2 = n2; w3 = n3;
    }
#pragma unroll
    for (int r = 0; r < C; ++r)
      *reinterpret_cast<float2*>(red + (kg * C + r) * 256 + c1) = acc[r];
  }
  __syncthreads();
  // ---------- reduce1 + bias (+lab) + relu -> h ----------
  if (t < 128 * C) {
    const int r  = t >> 7;
    const int c0 = 2 * (t & 127);
    float2 s = *reinterpret_cast<const float2*>(B1 + c0);
    if (uselab) {
      const int j = u1h[done + r] & 1;
      const float2 lv = *reinterpret_cast<const float2*>(lab + j * 256 + c0);
      s.x += lv.x; s.y += lv.y;
    }
#pragma unroll
    for (int q = 0; q < 8; ++q) {
      const float2 p = *reinterpret_cast<const float2*>(red + (q * C + r) * 256 + c0);
      s.x += p.x; s.y += p.y;
    }
    s.x = fmaxf(s.x, 0.f); s.y = fmaxf(s.y, 0.f);
    *reinterpret_cast<float2*>(h + r * 256 + c0) = s;
  }
  __syncthreads();
  // ---------- layer 2 ----------
  {
    const int c2 = 2 * ln;
    const float* wb2 = W2 + 16 * wv * 128 + c2;
    float2 acc[C];
#pragma unroll
    for (int r = 0; r < C; ++r) acc[r] = make_float2(0.f, 0.f);
    float2 w0 = *reinterpret_cast<const float2*>(wb2);
    float2 w1 = *reinterpret_cast<const float2*>(wb2 + 128);
    float2 w2 = *reinterpret_cast<const float2*>(wb2 + 256);
    float2 w3 = *reinterpret_cast<const float2*>(wb2 + 384);
#pragma unroll 1
    for (int blk = 0; blk < 4; ++blk) {
      const float* wn = wb2 + 4 * ((blk < 3) ? blk + 1 : 3) * 128;
      const float2 n0 = *reinterpret_cast<const float2*>(wn);
      const float2 n1 = *reinterpret_cast<const float2*>(wn + 128);
      const float2 n2 = *reinterpret_cast<const float2*>(wn + 256);
      const float2 n3 = *reinterpret_cast<const float2*>(wn + 384);
#pragma unroll
      for (int r = 0; r < C; ++r) {
        const float4 hv = *reinterpret_cast<const float4*>(h + r * 256 + 16 * wv + 4 * blk);
        acc[r].x = fmaf(hv.x,w0.x, fmaf(hv.y,w1.x, fmaf(hv.z,w2.x, fmaf(hv.w,w3.x, acc[r].x))));
        acc[r].y = fmaf(hv.x,w0.y, fmaf(hv.y,w1.y, fmaf(hv.z,w2.y, fmaf(hv.w,w3.y, acc[r].y))));
      }
      w0 = n0; w1 = n1; w2 = n2; w3 = n3;
    }
#pragma unroll
    for (int r = 0; r < C; ++r)
      *reinterpret_cast<float2*>(red + (wv * C + r) * 128 + c2) = acc[r];
  }
  __syncthreads();
  // ---------- reduce2 + bias -> eout ----------
  if (t < 64 * C) {
    const int r  = t >> 6;
    const int c0 = 2 * (t & 63);
    float2 s = *reinterpret_cast<const float2*>(B2 + c0);
#pragma unroll
    for (int q = 0; q < 16; ++q) {
      const float2 p = *reinterpret_cast<const float2*>(red + (q * C + r) * 128 + c0);
      s.x += p.x; s.y += p.y;
    }
    *reinterpret_cast<float2*>(eout + r * 128 + c0) = s;
  }
  __syncthreads();
}

// ---- fused check+speculative-bit chunk for deep levels (l in {5,6,7}) ----
// layer1: 2R partial rows (check + bit share z; label enters only as bias);
// reduce1: 3R h rows (check | bit+lab0 | bit+lab1); layer2 split-K 8: 3R
// rows; reduce2: check -> eout, bit -> spec[2][R][128]. Bit-time collapses
// to a select (l=5,6) or feeds leaves directly (l=7). R7: depth-1 weight
// prefetch on both streams; z read inline (reused by 16 FMAs) to fund the
// 16 prefetch regs within the 64-VGPR budget.
template <int R>
__device__ __forceinline__ void fused_chunk(
    const float* zl,
    const float* __restrict__ Wc1_, const float* __restrict__ Bc1_,
    const float* __restrict__ Wc2_, const float* __restrict__ Bc2_,
    const float* __restrict__ Wb1_, const float* __restrict__ Bb1_,
    const float* __restrict__ Wb2_, const float* __restrict__ Bb2_,
    const float* lab,
    float* red, float* h, float* eout, float* spec)
{
  const int t  = threadIdx.x;
  const int wv = t >> 6;
  const int ln = t & 63;
  // ---------- layer 1: 8 kg x 2 col-halves; 2R partial rows ----------
  {
    const int kg = wv >> 1;
    const int c1 = (wv & 1) * 128 + 2 * ln;
    const float* wcb = Wc1_ + 32 * kg * 256 + c1;
    const float* wbb = Wb1_ + 32 * kg * 256 + c1;
    const float* zb  = zl + 32 * kg;
    float2 ac[R], ab[R];
#pragma unroll
    for (int r = 0; r < R; ++r) { ac[r] = make_float2(0.f,0.f); ab[r] = make_float2(0.f,0.f); }
    float2 c0 = *reinterpret_cast<const float2*>(wcb);
    float2 c1v = *reinterpret_cast<const float2*>(wcb + 256);
    float2 c2v = *reinterpret_cast<const float2*>(wcb + 512);
    float2 c3v = *reinterpret_cast<const float2*>(wcb + 768);
    float2 b0 = *reinterpret_cast<const float2*>(wbb);
    float2 b1 = *reinterpret_cast<const float2*>(wbb + 256);
    float2 b2 = *reinterpret_cast<const float2*>(wbb + 512);
    float2 b3 = *reinterpret_cast<const float2*>(wbb + 768);
#pragma unroll 1
    for (int blk = 0; blk < 8; ++blk) {
      const int nb = 4 * ((blk < 7) ? blk + 1 : 7);
      const float* wcn = wcb + nb * 256;
      const float* wbn = wbb + nb * 256;
      const float2 nc0 = *reinterpret_cast<const float2*>(wcn);
      const float2 nc1 = *reinterpret_cast<const float2*>(wcn + 256);
      const float2 nc2 = *reinterpret_cast<const float2*>(wcn + 512);
      const float2 nc3 = *reinterpret_cast<const float2*>(wcn + 768);
      const float2 nb0 = *reinterpret_cast<const float2*>(wbn);
      const float2 nb1 = *reinterpret_cast<const float2*>(wbn + 256);
      const float2 nb2 = *reinterpret_cast<const float2*>(wbn + 512);
      const float2 nb3 = *reinterpret_cast<const float2*>(wbn + 768);
#pragma unroll
      for (int r = 0; r < R; ++r) {
        const float4 z = *reinterpret_cast<const float4*>(zb + r * 256 + 4 * blk);
        ac[r].x = fmaf(z.x,c0.x, fmaf(z.y,c1v.x, fmaf(z.z,c2v.x, fmaf(z.w,c3v.x, ac[r].x))));
        ac[r].y = fmaf(z.x,c0.y, fmaf(z.y,c1v.y, fmaf(z.z,c2v.y, fmaf(z.w,c3v.y, ac[r].y))));
        ab[r].x = fmaf(z.x,b0.x, fmaf(z.y,b1.x, fmaf(z.z,b2.x, fmaf(z.w,b3.x, ab[r].x))));
        ab[r].y = fmaf(z.x,b0.y, fmaf(z.y,b1.y, fmaf(z.z,b2.y, fmaf(z.w,b3.y, ab[r].y))));
      }
      c0 = nc0; c1v = nc1; c2v = nc2; c3v = nc3;
      b0 = nb0; b1 = nb1; b2 = nb2; b3 = nb3;
    }
#pragma unroll
    for (int r = 0; r < R; ++r) {
      *reinterpret_cast<float2*>(red + (kg * 2 * R + r) * 256 + c1) = ac[r];
      *reinterpret_cast<float2*>(red + (kg * 2 * R + R + r) * 256 + c1) = ab[r];
    }
  }
  __syncthreads();
  // ---------- reduce1 -> h: 3R rows ----------
  for (int idx = t; idx < 3 * R * 128; idx += NTHR) {
    const int r  = idx >> 7;
    const int c0 = 2 * (idx & 127);
    const int pr = (r < 2 * R) ? r : r - R;     // bit partials shared by variants
    float2 s;
    if (r < R) {
      s = *reinterpret_cast<const float2*>(Bc1_ + c0);
    } else {
      s = *reinterpret_cast<const float2*>(Bb1_ + c0);
      const float2 lv = *reinterpret_cast<const float2*>(lab + ((r < 2 * R) ? 0 : 256) + c0);
      s.x += lv.x; s.y += lv.y;
    }
#pragma unroll
    for (int q = 0; q < 8; ++q) {
      const float2 p = *reinterpret_cast<const float2*>(red + (q * 2 * R + pr) * 256 + c0);
      s.x += p.x; s.y += p.y;
    }
    s.x = fmaxf(s.x, 0.f); s.y = fmaxf(s.y, 0.f);
    *reinterpret_cast<float2*>(h + r * 256 + c0) = s;
  }
  __syncthreads();
  // ---------- layer 2: 8 kg x 2 col-halves (1 col/lane); 3R rows ----------
  {
    const int kg = wv >> 1;
    const int c2 = (wv & 1) * 64 + ln;
    const float* wcb = Wc2_ + 32 * kg * 128 + c2;
    const float* wbb = Wb2_ + 32 * kg * 128 + c2;
    float acc[3 * R];
#pragma unroll
    for (int r = 0; r < 3 * R; ++r) acc[r] = 0.f;
    float c0v = wcb[0], c1v = wcb[128], c2v = wcb[256], c3v = wcb[384];
    float b0v = wbb[0], b1v = wbb[128], b2v = wbb[256], b3v = wbb[384];
#pragma unroll 1
    for (int blk = 0; blk < 8; ++blk) {
      const int nb = 4 * ((blk < 7) ? blk + 1 : 7);
      const float* wcn = wcb + nb * 128;
      const float* wbn = wbb + nb * 128;
      const float nc0 = wcn[0], nc1 = wcn[128], nc2 = wcn[256], nc3 = wcn[384];
      const float nb0 = wbn[0], nb1 = wbn[128], nb2 = wbn[256], nb3 = wbn[384];
      const float* hb = h + 32 * kg + 4 * blk;
#pragma unroll
      for (int r = 0; r < 3 * R; ++r) {
        const float4 hv = *reinterpret_cast<const float4*>(hb + r * 256);
        if (r < R)
          acc[r] = fmaf(hv.x,c0v, fmaf(hv.y,c1v, fmaf(hv.z,c2v, fmaf(hv.w,c3v, acc[r]))));
        else
          acc[r] = fmaf(hv.x,b0v, fmaf(hv.y,b1v, fmaf(hv.z,b2v, fmaf(hv.w,b3v, acc[r]))));
      }
      c0v = nc0; c1v = nc1; c2v = nc2; c3v = nc3;
      b0v = nb0; b1v = nb1; b2v = nb2; b3v = nb3;
    }
#pragma unroll
    for (int r = 0; r < 3 * R; ++r)
      red[(kg * 3 * R + r) * 128 + c2] = acc[r];
  }
  __syncthreads();
  // ---------- reduce2: check -> eout, bit -> spec[2][R][128] ----------
  for (int idx = t; idx < 3 * R * 128; idx += NTHR) {
    const int r = idx >> 7;
    const int c = idx & 127;
    float s = (r < R) ? Bc2_[c] : Bb2_[c];
#pragma unroll
    for (int q = 0; q < 8; ++q) s += red[(q * 3 * R + r) * 128 + c];
    if (r < R)            eout[r * 128 + c] = s;
    else if (r < 2 * R)   spec[(r - R) * 128 + c] = s;
    else                  spec[R * 128 + (r - 2 * R) * 128 + c] = s;
  }
  __syncthreads();
}

__global__ void sc_setup(const int* __restrict__ info_set,
                         const float* __restrict__ E_obs,
                         const float* __restrict__ E_lab,
                         const float* __restrict__ Wb1,
                         int* __restrict__ pos2k, float* __restrict__ lab1,
                         float* __restrict__ eroot)
{
  const int t = threadIdx.x;   // 256 threads
  pos2k[t] = -1;
  __syncthreads();
  if (t < 128) pos2k[info_set[t]] = t;
  eroot[t] = E_obs[2 * 128 + (t & 127)];
  for (int j = 0; j < 2; ++j) {
    float s = 0.0f;
    for (int k = 0; k < 128; ++k)
      s = fmaf(E_lab[j * 128 + k], Wb1[(256 + k) * 256 + t], s);
    lab1[j * 256 + t] = s;
  }
}

__global__ __launch_bounds__(NTHR)
__attribute__((amdgpu_waves_per_eu(4, 4)))
void sc_main(const int* __restrict__ info_bits, const float* __restrict__ rin,
             const float* __restrict__ Wc1, const float* __restrict__ bc1,
             const float* __restrict__ Wc2, const float* __restrict__ bc2,
             const float* __restrict__ Wb1, const float* __restrict__ bb1,
             const float* __restrict__ Wb2, const float* __restrict__ bb2,
             const float* __restrict__ Wl, const float* __restrict__ bl,
             const int* __restrict__ pos2k, const float* __restrict__ lab1_g,
             const float* __restrict__ eroot_g,
             float* __restrict__ wsall, float* __restrict__ out)
{
  const int b = blockIdx.x;
  const int t = threadIdx.x;
  float* e1g = wsall + (size_t)b * EG_STRIDE;      // level-1 e (global)

  __shared__ __align__(16) float red[16384];       // 64 KB split-K partials
  __shared__ __align__(16) float h_lds[3072];      // 12 KB hidden / lvl-1 z-stage
  __shared__ __align__(16) float scratch[1792];    //  7 KB: lvl-0 out UNION specs
                                                   //  spec5[0,1024) spec6[1024,1536) spec7[1536,1792)
  __shared__ __align__(16) float e2[8192];         // 32 KB level-2 e
  __shared__ __align__(16) float e3[4096];         // 16 KB level-3 e
  __shared__ __align__(16) float e4[2048];         //  8 KB level-4 e
  __shared__ __align__(16) float e5678[1920];      // levels 5..8: 8,4,2,1 rows
  __shared__ __align__(16) float lab_lds[512];
  __shared__ __align__(16) float eroot[256];
  __shared__ float rrow[256];
  __shared__ float wl_lds[132];                    // Wl[128] + bl at [128]
  __shared__ float dots[4];                        // e8 / spec7[0] / spec7[1] LLR dots
  __shared__ int   xh[520];
  __shared__ int   ibits[128];
  __shared__ int   p2k_l[256];

  float* xO = out;
  float* fO = out + 32768;
  float* uO = out + 65536;
  float* pO = out + 98304;
  float* rO = out + 131072;

  // ---- prologue: preload constants, hoist input-independent outputs ----
  if (t < 512) lab_lds[t] = lab1_g[t];
  if (t < 256) {
    eroot[t]  = eroot_g[t];
    const int k = pos2k[t];
    p2k_l[t]  = k;
    const float rv = rin[b * 256 + t];
    rrow[t]   = rv;
    rO[b * 256 + t] = rv;
    fO[b * 256 + t] = (k >= 0) ? 2.0f : 1.0f;
  }
  if (t < 128) { ibits[t] = info_bits[b * 128 + t]; wl_lds[t] = Wl[t]; }
  if (t == 128) wl_lds[128] = bl[0];
  if (t == 0) { xh[512] = 0; xh[513] = 1; }        // constant u1h for lvl-0 bit
  __syncthreads();

  // ---- levels 1..4: C8 chunks (R5-proven; R6's C16 regressed) ----
  auto run_level = [&](int l, bool isbit) {
    const int rows = 128 >> l;
    const float* W1 = isbit ? Wb1 : Wc1;
    const float* B1 = isbit ? bb1 : bc1;
    const float* W2 = isbit ? Wb2 : Wc2;
    const float* B2 = isbit ? bb2 : bc2;
    const int* u1h = xh + xoff(l);
    const float* ein; float* eo;
    switch (l) {
      case 1:  ein = nullptr; eo = e2;    break;
      case 2:  ein = e2;      eo = e3;    break;
      case 3:  ein = e3;      eo = e4;    break;
      default: ein = e4;      eo = e5678; break;   // l == 4
    }
    for (int done = 0; done < rows; done += 8) {
      const float* zl;
      if (l == 1) {   // stage 8 z-rows into h_lds (dead until reduce1 rewrites)
        const float4* src = reinterpret_cast<const float4*>(e1g + done * 256);
        for (int i4 = t; i4 < 512; i4 += NTHR)
          reinterpret_cast<float4*>(h_lds)[i4] = src[i4];
        __syncthreads();
        zl = h_lds;
      } else {
        zl = ein + done * 256;
      }
      mlp_chunk<8>(zl, 256, W1, B1, W2, B2, lab_lds, isbit, u1h, done,
                   red, h_lds, eo + done * 128);
    }
  };

  // ---- level 0 special: check rows all identical (z = eroot); bit rows take
  // only 2 values. Compute 1 (check) or 2 (bit) rows, broadcast into e1. ----
  auto run_level0 = [&](bool isbit) {
    if (!isbit) {
      mlp_chunk<1>(eroot, 0, Wc1, bc1, Wc2, bc2, lab_lds, false, xh, 0, red, h_lds, scratch);
      for (int i4 = t; i4 < 4096; i4 += NTHR)
        reinterpret_cast<float4*>(e1g)[i4] =
            reinterpret_cast<const float4*>(scratch)[i4 & 31];
    } else {
      mlp_chunk<2>(eroot, 0, Wb1, bb1, Wb2, bb2, lab_lds, true, xh + 512, 0, red, h_lds, scratch);
      for (int i4 = t; i4 < 4096; i4 += NTHR)
        reinterpret_cast<float4*>(e1g)[i4] =
            reinterpret_cast<const float4*>(scratch)[(xh[i4 >> 5] & 1) * 32 + (i4 & 31)];
    }
    __syncthreads();
  };

  // ---- fused check+spec for l in {5,6,7} ----
  auto run_fused = [&](int l) {
    if (l == 5)
      fused_chunk<4>(e5678, Wc1, bc1, Wc2, bc2, Wb1, bb1, Wb2, bb2, lab_lds,
                     red, h_lds, e5678 + 1024, scratch);
    else if (l == 6)
      fused_chunk<2>(e5678 + 1024, Wc1, bc1, Wc2, bc2, Wb1, bb1, Wb2, bb2, lab_lds,
                     red, h_lds, e5678 + 1536, scratch + 1024);
    else
      fused_chunk<1>(e5678 + 1536, Wc1, bc1, Wc2, bc2, Wb1, bb1, Wb2, bb2, lab_lds,
                     red, h_lds, e5678 + 1792, scratch + 1536);
  };

  // ---- bit-time select for l in {5,6}: child e row r = spec[u1h[r]][r] ----
  auto do_select = [&](int l) {
    const int R = 128 >> l;
    const float* spec = scratch + ((l == 5) ? 0 : 1024);
    float* eo = (l == 5) ? (e5678 + 1024) : (e5678 + 1536);
    const int* u1h = xh + xoff(l);
    if (t < R * 128) {
      const int r = t >> 7;
      eo[t] = spec[(u1h[r] & 1) * R * 128 + t];
    }
    __syncthreads();
  };

  // ---- leaf pair: one parallel dot phase (3 waves), one scalar decide ----
  auto do_dots = [&]() {
    if (t < 192) {
      const int g = t >> 6, l6 = t & 63;
      const float* row = (g == 0) ? (e5678 + 1792) : (scratch + 1536 + (g - 1) * 128);
      float partial = row[l6] * wl_lds[l6] + row[l6 + 64] * wl_lds[l6 + 64];
#pragma unroll
      for (int m = 32; m >= 1; m >>= 1) partial += __shfl_xor(partial, m);
      if (l6 == 0) dots[g] = partial + wl_lds[128];
    }
    __syncthreads();
  };
  auto do_decide = [&](int i, int s) {   // i even; s = ctz(i+2)
    if (t == 0) {
      int xv[2];
#pragma unroll
      for (int q = 0; q < 2; ++q) {
        const float dv = (q == 0) ? dots[0] : dots[1 + (xv[0] & 1)];
        const float p  = 1.0f / (1.0f + expf(-dv));
        const float rv = rrow[i + q];
        const int  hd     = (rv > p) ? 1 : 0;
        const bool frozen = fabsf(p - 0.5f) > 0.25f;
        const int  k  = p2k_l[i + q];
        const int  fc = (k >= 0) ? ibits[k] : 2;
        xv[q] = (fc == 2 || frozen) ? hd : fc;
        pO[b * 256 + i + q] = p;
        uO[b * 256 + i + q] = (float)xv[q];
      }
      const int side = (1 < s) ? 1 : 0;            // combine j=1 (level 7)
      const int base = xoff(6) + side * 2;
      xh[base]     = xv[0] ^ xv[1];
      xh[base + 1] = xv[1];
    }
    __syncthreads();
  };

  auto do_combine = [&](int l, int side) {
    const int n = 256 >> l, half = n >> 1;
    if (t < half) {
      const int u1 = xh[xoff(l) + t];
      const int u2 = xh[xoff(l) + half + t];
      if (l > 0) {
        const int base = xoff(l - 1) + side * n;
        xh[base + 2 * t]     = u1 ^ u2;
        xh[base + 2 * t + 1] = u2;
      } else {
        xO[b * 256 + 2 * t]     = (float)(u1 ^ u2);
        xO[b * 256 + 2 * t + 1] = (float)u2;
      }
    }
    __syncthreads();
  };

  // ---- SC traversal ----
  int i = 0, l = 0;
  bool isbit = false;
  while (true) {
    if (l >= 5) {
      if (isbit) do_select(l);           // l is 5 or 6 here
      else       run_fused(l);
    } else if (l == 0) {
      run_level0(isbit);
    } else {
      run_level(l, isbit);
    }
    if (l < 7) { ++l; isbit = false; continue; }
    // l == 7 check: f7 just ran -> leaves i, i+1
    do_dots();
    const int s = __builtin_ctz(i + 2);
    do_decide(i, s);
    if (i == 254) {
      for (int j = 2; j <= 8; ++j) do_combine(8 - j, (j < s) ? 1 : 0);
      break;
    }
    i += 2;
    for (int j = 2; j <= s; ++j) do_combine(8 - j, (j < s) ? 1 : 0);
    l = 7 - s;
    isbit = true;
  }
}

extern "C" void kernel_launch(void* const* d_in, const int* in_sizes, int n_in,
                              void* d_out, int out_size, void* d_ws, size_t ws_size,
                              hipStream_t stream)
{
  const int*   info_bits = (const int*)  d_in[0];
  const float* rin       = (const float*)d_in[1];
  const int*   info_set  = (const int*)  d_in[2];
  const float* E_obs     = (const float*)d_in[3];
  const float* E_lab     = (const float*)d_in[4];
  const float* Wc1 = (const float*)d_in[5];
  const float* bc1 = (const float*)d_in[6];
  const float* Wc2 = (const float*)d_in[7];
  const float* bc2 = (const float*)d_in[8];
  const float* Wb1 = (const float*)d_in[9];
  const float* bb1 = (const float*)d_in[10];
  const float* Wb2 = (const float*)d_in[11];
  const float* bb2 = (const float*)d_in[12];
  const float* Wl  = (const float*)d_in[13];
  const float* bl  = (const float*)d_in[14];

  int*   pos2k = (int*)d_ws;                 // 256 ints
  float* lab1  = (float*)d_ws + 256;         // 512 floats
  float* eroot = (float*)d_ws + 768;         // 256 floats
  float* wsall = (float*)d_ws + 1024;        // 128 x EG_STRIDE floats

  hipLaunchKernelGGL(sc_setup, dim3(1), dim3(256), 0, stream,
                     info_set, E_obs, E_lab, Wb1, pos2k, lab1, eroot);
  hipLaunchKernelGGL(sc_main, dim3(128), dim3(NTHR), 0, stream,
                     info_bits, rin,
                     Wc1, bc1, Wc2, bc2, Wb1, bb1, Wb2, bb2, Wl, bl,
                     pos2k, lab1, eroot, wsall, (float*)d_out);
}

// Round 8
// 3353.251 us; speedup vs baseline: 1.1921x; 1.1168x over previous
//
#include <hip/hip_runtime.h>
#include <math.h>

#define NTHR 1024

constexpr int EG_STRIDE = 16384;   // floats per batch: e1 only (128 rows x 128)

__device__ __forceinline__ int xoff(int l) { return 512 - (512 >> l); }   // l in 0..7

// ---- MLP chunk, C rows: R3-proven register shape + depth-1 weight prefetch.
// layer1: 16 waves = 8 kg (32k) x 2 col-halves, 2 cols/lane. layer2: 16 kg.
// `#pragma unroll 1` on k-loops is load-bearing (R1/R2: full unroll ->
// scheduler hoists loads past the 64-VGPR cap -> 21 GB scratch spill).
template <int C>
__device__ __forceinline__ void mlp_chunk(
    const float* zl, int zstr,
    const float* __restrict__ W1, const float* __restrict__ B1,
    const float* __restrict__ W2, const float* __restrict__ B2,
    const float* lab, bool uselab, const int* u1h, int done,
    float* red, float* h, float* eout)
{
  const int t  = threadIdx.x;
  const int wv = t >> 6;
  const int ln = t & 63;
  // ---------- layer 1 ----------
  {
    const int kg = wv >> 1;
    const int c1 = (wv & 1) * 128 + 2 * ln;
    const float* wb = W1 + 32 * kg * 256 + c1;
    const float* zb = zl + 32 * kg;
    float2 acc[C];
#pragma unroll
    for (int r = 0; r < C; ++r) acc[r] = make_float2(0.f, 0.f);
    float2 w0 = *reinterpret_cast<const float2*>(wb);
    float2 w1 = *reinterpret_cast<const float2*>(wb + 256);
    float2 w2 = *reinterpret_cast<const float2*>(wb + 512);
    float2 w3 = *reinterpret_cast<const float2*>(wb + 768);
#pragma unroll 1
    for (int blk = 0; blk < 8; ++blk) {
      const float* wn = wb + 4 * ((blk < 7) ? blk + 1 : 7) * 256;
      const float2 n0 = *reinterpret_cast<const float2*>(wn);
      const float2 n1 = *reinterpret_cast<const float2*>(wn + 256);
      const float2 n2 = *reinterpret_cast<const float2*>(wn + 512);
      const float2 n3 = *reinterpret_cast<const float2*>(wn + 768);
#pragma unroll
      for (int r = 0; r < C; ++r) {
        const float4 z = *reinterpret_cast<const float4*>(zb + r * zstr + 4 * blk);
        acc[r].x = fmaf(z.x,w0.x, fmaf(z.y,w1.x, fmaf(z.z,w2.x, fmaf(z.w,w3.x, acc[r].x))));
        acc[r].y = fmaf(z.x,w0.y, fmaf(z.y,w1.y, fmaf(z.z,w2.y, fmaf(z.w,w3.y, acc[r].y))));
      }
      w0 = n0; w1 = n1; w2 = n2; w3 = n3;
    }
#pragma unroll
    for (int r = 0; r < C; ++r)
      *reinterpret_cast<float2*>(red + (kg * C + r) * 256 + c1) = acc[r];
  }
  __syncthreads();
  // ---------- reduce1 + bias (+lab) + relu -> h ----------
  if (t < 128 * C) {
    const int r  = t >> 7;
    const int c0 = 2 * (t & 127);
    float2 s = *reinterpret_cast<const float2*>(B1 + c0);
    if (uselab) {
      const int j = u1h[done + r] & 1;
      const float2 lv = *reinterpret_cast<const float2*>(lab + j * 256 + c0);
      s.x += lv.x; s.y += lv.y;
    }
#pragma unroll
    for (int q = 0; q < 8; ++q) {
      const float2 p = *reinterpret_cast<const float2*>(red + (q * C + r) * 256 + c0);
      s.x += p.x; s.y += p.y;
    }
    s.x = fmaxf(s.x, 0.f); s.y = fmaxf(s.y, 0.f);
    *reinterpret_cast<float2*>(h + r * 256 + c0) = s;
  }
  __syncthreads();
  // ---------- layer 2 ----------
  {
    const int c2 = 2 * ln;
    const float* wb2 = W2 + 16 * wv * 128 + c2;
    float2 acc[C];
#pragma unroll
    for (int r = 0; r < C; ++r) acc[r] = make_float2(0.f, 0.f);
    float2 w0 = *reinterpret_cast<const float2*>(wb2);
    float2 w1 = *reinterpret_cast<const float2*>(wb2 + 128);
    float2 w2 = *reinterpret_cast<const float2*>(wb2 + 256);
    float2 w3 = *reinterpret_cast<const float2*>(wb2 + 384);
#pragma unroll 1
    for (int blk = 0; blk < 4; ++blk) {
      const float* wn = wb2 + 4 * ((blk < 3) ? blk + 1 : 3) * 128;
      const float2 n0 = *reinterpret_cast<const float2*>(wn);
      const float2 n1 = *reinterpret_cast<const float2*>(wn + 128);
      const float2 n2 = *reinterpret_cast<const float2*>(wn + 256);
      const float2 n3 = *reinterpret_cast<const float2*>(wn + 384);
#pragma unroll
      for (int r = 0; r < C; ++r) {
        const float4 hv = *reinterpret_cast<const float4*>(h + r * 256 + 16 * wv + 4 * blk);
        acc[r].x = fmaf(hv.x,w0.x, fmaf(hv.y,w1.x, fmaf(hv.z,w2.x, fmaf(hv.w,w3.x, acc[r].x))));
        acc[r].y = fmaf(hv.x,w0.y, fmaf(hv.y,w1.y, fmaf(hv.z,w2.y, fmaf(hv.w,w3.y, acc[r].y))));
      }
      w0 = n0; w1 = n1; w2 = n2; w3 = n3;
    }
#pragma unroll
    for (int r = 0; r < C; ++r)
      *reinterpret_cast<float2*>(red + (wv * C + r) * 128 + c2) = acc[r];
  }
  __syncthreads();
  // ---------- reduce2 + bias -> eout ----------
  if (t < 64 * C) {
    const int r  = t >> 6;
    const int c0 = 2 * (t & 63);
    float2 s = *reinterpret_cast<const float2*>(B2 + c0);
#pragma unroll
    for (int q = 0; q < 16; ++q) {
      const float2 p = *reinterpret_cast<const float2*>(red + (q * C + r) * 128 + c0);
      s.x += p.x; s.y += p.y;
    }
    *reinterpret_cast<float2*>(eout + r * 128 + c0) = s;
  }
  __syncthreads();
}

// ---- fused check+speculative-bit chunk for l in {5,6} ----
// layer1: 2R partial rows (check + bit share z; label enters only as bias);
// reduce1: 3R h rows (check | bit+lab0 | bit+lab1); layer2 split-K 8: 3R
// rows; reduce2: check -> eout, bit -> spec[2][R][128]. Bit-time collapses
// to a select. Depth-1 weight prefetch on both streams.
template <int R>
__device__ __forceinline__ void fused_chunk(
    const float* zl,
    const float* __restrict__ Wc1_, const float* __restrict__ Bc1_,
    const float* __restrict__ Wc2_, const float* __restrict__ Bc2_,
    const float* __restrict__ Wb1_, const float* __restrict__ Bb1_,
    const float* __restrict__ Wb2_, const float* __restrict__ Bb2_,
    const float* lab,
    float* red, float* h, float* eout, float* spec)
{
  const int t  = threadIdx.x;
  const int wv = t >> 6;
  const int ln = t & 63;
  // ---------- layer 1: 8 kg x 2 col-halves; 2R partial rows ----------
  {
    const int kg = wv >> 1;
    const int c1 = (wv & 1) * 128 + 2 * ln;
    const float* wcb = Wc1_ + 32 * kg * 256 + c1;
    const float* wbb = Wb1_ + 32 * kg * 256 + c1;
    const float* zb  = zl + 32 * kg;
    float2 ac[R], ab[R];
#pragma unroll
    for (int r = 0; r < R; ++r) { ac[r] = make_float2(0.f,0.f); ab[r] = make_float2(0.f,0.f); }
    float2 c0 = *reinterpret_cast<const float2*>(wcb);
    float2 c1v = *reinterpret_cast<const float2*>(wcb + 256);
    float2 c2v = *reinterpret_cast<const float2*>(wcb + 512);
    float2 c3v = *reinterpret_cast<const float2*>(wcb + 768);
    float2 b0 = *reinterpret_cast<const float2*>(wbb);
    float2 b1 = *reinterpret_cast<const float2*>(wbb + 256);
    float2 b2 = *reinterpret_cast<const float2*>(wbb + 512);
    float2 b3 = *reinterpret_cast<const float2*>(wbb + 768);
#pragma unroll 1
    for (int blk = 0; blk < 8; ++blk) {
      const int nb = 4 * ((blk < 7) ? blk + 1 : 7);
      const float* wcn = wcb + nb * 256;
      const float* wbn = wbb + nb * 256;
      const float2 nc0 = *reinterpret_cast<const float2*>(wcn);
      const float2 nc1 = *reinterpret_cast<const float2*>(wcn + 256);
      const float2 nc2 = *reinterpret_cast<const float2*>(wcn + 512);
      const float2 nc3 = *reinterpret_cast<const float2*>(wcn + 768);
      const float2 nb0 = *reinterpret_cast<const float2*>(wbn);
      const float2 nb1 = *reinterpret_cast<const float2*>(wbn + 256);
      const float2 nb2 = *reinterpret_cast<const float2*>(wbn + 512);
      const float2 nb3 = *reinterpret_cast<const float2*>(wbn + 768);
#pragma unroll
      for (int r = 0; r < R; ++r) {
        const float4 z = *reinterpret_cast<const float4*>(zb + r * 256 + 4 * blk);
        ac[r].x = fmaf(z.x,c0.x, fmaf(z.y,c1v.x, fmaf(z.z,c2v.x, fmaf(z.w,c3v.x, ac[r].x))));
        ac[r].y = fmaf(z.x,c0.y, fmaf(z.y,c1v.y, fmaf(z.z,c2v.y, fmaf(z.w,c3v.y, ac[r].y))));
        ab[r].x = fmaf(z.x,b0.x, fmaf(z.y,b1.x, fmaf(z.z,b2.x, fmaf(z.w,b3.x, ab[r].x))));
        ab[r].y = fmaf(z.x,b0.y, fmaf(z.y,b1.y, fmaf(z.z,b2.y, fmaf(z.w,b3.y, ab[r].y))));
      }
      c0 = nc0; c1v = nc1; c2v = nc2; c3v = nc3;
      b0 = nb0; b1 = nb1; b2 = nb2; b3 = nb3;
    }
#pragma unroll
    for (int r = 0; r < R; ++r) {
      *reinterpret_cast<float2*>(red + (kg * 2 * R + r) * 256 + c1) = ac[r];
      *reinterpret_cast<float2*>(red + (kg * 2 * R + R + r) * 256 + c1) = ab[r];
    }
  }
  __syncthreads();
  // ---------- reduce1 -> h: 3R rows ----------
  for (int idx = t; idx < 3 * R * 128; idx += NTHR) {
    const int r  = idx >> 7;
    const int c0 = 2 * (idx & 127);
    const int pr = (r < 2 * R) ? r : r - R;     // bit partials shared by variants
    float2 s;
    if (r < R) {
      s = *reinterpret_cast<const float2*>(Bc1_ + c0);
    } else {
      s = *reinterpret_cast<const float2*>(Bb1_ + c0);
      const float2 lv = *reinterpret_cast<const float2*>(lab + ((r < 2 * R) ? 0 : 256) + c0);
      s.x += lv.x; s.y += lv.y;
    }
#pragma unroll
    for (int q = 0; q < 8; ++q) {
      const float2 p = *reinterpret_cast<const float2*>(red + (q * 2 * R + pr) * 256 + c0);
      s.x += p.x; s.y += p.y;
    }
    s.x = fmaxf(s.x, 0.f); s.y = fmaxf(s.y, 0.f);
    *reinterpret_cast<float2*>(h + r * 256 + c0) = s;
  }
  __syncthreads();
  // ---------- layer 2: 8 kg x 2 col-halves (1 col/lane); 3R rows ----------
  {
    const int kg = wv >> 1;
    const int c2 = (wv & 1) * 64 + ln;
    const float* wcb = Wc2_ + 32 * kg * 128 + c2;
    const float* wbb = Wb2_ + 32 * kg * 128 + c2;
    float acc[3 * R];
#pragma unroll
    for (int r = 0; r < 3 * R; ++r) acc[r] = 0.f;
    float c0v = wcb[0], c1v = wcb[128], c2v = wcb[256], c3v = wcb[384];
    float b0v = wbb[0], b1v = wbb[128], b2v = wbb[256], b3v = wbb[384];
#pragma unroll 1
    for (int blk = 0; blk < 8; ++blk) {
      const int nb = 4 * ((blk < 7) ? blk + 1 : 7);
      const float* wcn = wcb + nb * 128;
      const float* wbn = wbb + nb * 128;
      const float nc0 = wcn[0], nc1 = wcn[128], nc2 = wcn[256], nc3 = wcn[384];
      const float nb0 = wbn[0], nb1 = wbn[128], nb2 = wbn[256], nb3 = wbn[384];
      const float* hb = h + 32 * kg + 4 * blk;
#pragma unroll
      for (int r = 0; r < 3 * R; ++r) {
        const float4 hv = *reinterpret_cast<const float4*>(hb + r * 256);
        if (r < R)
          acc[r] = fmaf(hv.x,c0v, fmaf(hv.y,c1v, fmaf(hv.z,c2v, fmaf(hv.w,c3v, acc[r]))));
        else
          acc[r] = fmaf(hv.x,b0v, fmaf(hv.y,b1v, fmaf(hv.z,b2v, fmaf(hv.w,b3v, acc[r]))));
      }
      c0v = nc0; c1v = nc1; c2v = nc2; c3v = nc3;
      b0v = nb0; b1v = nb1; b2v = nb2; b3v = nb3;
    }
#pragma unroll
    for (int r = 0; r < 3 * R; ++r)
      red[(kg * 3 * R + r) * 128 + c2] = acc[r];
  }
  __syncthreads();
  // ---------- reduce2: check -> eout, bit -> spec[2][R][128] ----------
  for (int idx = t; idx < 3 * R * 128; idx += NTHR) {
    const int r = idx >> 7;
    const int c = idx & 127;
    float s = (r < R) ? Bc2_[c] : Bb2_[c];
#pragma unroll
    for (int q = 0; q < 8; ++q) s += red[(q * 3 * R + r) * 128 + c];
    if (r < R)            eout[r * 128 + c] = s;
    else if (r < 2 * R)   spec[(r - R) * 128 + c] = s;
    else                  spec[R * 128 + (r - 2 * R) * 128 + c] = s;
  }
  __syncthreads();
}

// ---- l7 leaf-collapsed chunk (R8): e8/spec7 feed ONLY the leaf LLR dots, so
// layer2 folds into precomputed vectors: cv = Wc2@Wl, bv = Wb2@Wl, consts
// cc = bc2@Wl+bl, cb = bb2@Wl+bl. One exec = layer1 (Wc1+Wb1, 512 KB — no
// W2 stream), reduce1 -> 3 h rows, three 256-dots -> dots[0..2] (pre-sigmoid
// logits: check, bit+lab0, bit+lab1). Kills 256 KB + 2 phases per exec.
__device__ __forceinline__ void fused7_dot(
    const float* zl,
    const float* __restrict__ Wc1_, const float* __restrict__ Bc1_,
    const float* __restrict__ Wb1_, const float* __restrict__ Bb1_,
    const float* lab, const float* cvb,   // [0,256)=cv [256,512)=bv [512]=cc [513]=cb
    float* red, float* h, float* dots)
{
  const int t  = threadIdx.x;
  const int wv = t >> 6;
  const int ln = t & 63;
  // ---------- layer 1: 8 kg x 2 col-halves; 2 partial rows (check, bit) ----
  {
    const int kg = wv >> 1;
    const int c1 = (wv & 1) * 128 + 2 * ln;
    const float* wcb = Wc1_ + 32 * kg * 256 + c1;
    const float* wbb = Wb1_ + 32 * kg * 256 + c1;
    const float* zb  = zl + 32 * kg;
    float2 ac = make_float2(0.f, 0.f), ab = make_float2(0.f, 0.f);
    float2 c0 = *reinterpret_cast<const float2*>(wcb);
    float2 c1v = *reinterpret_cast<const float2*>(wcb + 256);
    float2 c2v = *reinterpret_cast<const float2*>(wcb + 512);
    float2 c3v = *reinterpret_cast<const float2*>(wcb + 768);
    float2 b0 = *reinterpret_cast<const float2*>(wbb);
    float2 b1 = *reinterpret_cast<const float2*>(wbb + 256);
    float2 b2 = *reinterpret_cast<const float2*>(wbb + 512);
    float2 b3 = *reinterpret_cast<const float2*>(wbb + 768);
#pragma unroll 1
    for (int blk = 0; blk < 8; ++blk) {
      const int nb = 4 * ((blk < 7) ? blk + 1 : 7);
      const float* wcn = wcb + nb * 256;
      const float* wbn = wbb + nb * 256;
      const float2 nc0 = *reinterpret_cast<const float2*>(wcn);
      const float2 nc1 = *reinterpret_cast<const float2*>(wcn + 256);
      const float2 nc2 = *reinterpret_cast<const float2*>(wcn + 512);
      const float2 nc3 = *reinterpret_cast<const float2*>(wcn + 768);
      const float2 nb0 = *reinterpret_cast<const float2*>(wbn);
      const float2 nb1 = *reinterpret_cast<const float2*>(wbn + 256);
      const float2 nb2 = *reinterpret_cast<const float2*>(wbn + 512);
      const float2 nb3 = *reinterpret_cast<const float2*>(wbn + 768);
      const float4 z = *reinterpret_cast<const float4*>(zb + 4 * blk);
      ac.x = fmaf(z.x,c0.x, fmaf(z.y,c1v.x, fmaf(z.z,c2v.x, fmaf(z.w,c3v.x, ac.x))));
      ac.y = fmaf(z.x,c0.y, fmaf(z.y,c1v.y, fmaf(z.z,c2v.y, fmaf(z.w,c3v.y, ac.y))));
      ab.x = fmaf(z.x,b0.x, fmaf(z.y,b1.x, fmaf(z.z,b2.x, fmaf(z.w,b3.x, ab.x))));
      ab.y = fmaf(z.x,b0.y, fmaf(z.y,b1.y, fmaf(z.z,b2.y, fmaf(z.w,b3.y, ab.y))));
      c0 = nc0; c1v = nc1; c2v = nc2; c3v = nc3;
      b0 = nb0; b1 = nb1; b2 = nb2; b3 = nb3;
    }
    *reinterpret_cast<float2*>(red + (kg * 2 + 0) * 256 + c1) = ac;
    *reinterpret_cast<float2*>(red + (kg * 2 + 1) * 256 + c1) = ab;
  }
  __syncthreads();
  // ---------- reduce1 -> h: 3 rows (check | bit+lab0 | bit+lab1) ----------
  if (t < 384) {
    const int r  = t >> 7;
    const int c0 = 2 * (t & 127);
    const int pr = (r < 2) ? r : 1;
    float2 s;
    if (r < 1) {
      s = *reinterpret_cast<const float2*>(Bc1_ + c0);
    } else {
      s = *reinterpret_cast<const float2*>(Bb1_ + c0);
      const float2 lv = *reinterpret_cast<const float2*>(lab + ((r < 2) ? 0 : 256) + c0);
      s.x += lv.x; s.y += lv.y;
    }
#pragma unroll
    for (int q = 0; q < 8; ++q) {
      const float2 p = *reinterpret_cast<const float2*>(red + (q * 2 + pr) * 256 + c0);
      s.x += p.x; s.y += p.y;
    }
    s.x = fmaxf(s.x, 0.f); s.y = fmaxf(s.y, 0.f);
    *reinterpret_cast<float2*>(h + r * 256 + c0) = s;
  }
  __syncthreads();
  // ---------- dots: 3 waves, one 256-dot each (h row @ cv/bv) ----------
  if (t < 192) {
    const int g  = t >> 6;
    const int k0 = 4 * (t & 63);
    const float4 hv = *reinterpret_cast<const float4*>(h + g * 256 + k0);
    const float4 vv = *reinterpret_cast<const float4*>(cvb + ((g == 0) ? 0 : 256) + k0);
    float s = hv.x * vv.x + hv.y * vv.y + hv.z * vv.z + hv.w * vv.w;
#pragma unroll
    for (int m = 32; m >= 1; m >>= 1) s += __shfl_xor(s, m);
    if ((t & 63) == 0) dots[g] = s + cvb[512 + ((g == 0) ? 0 : 1)];
  }
  __syncthreads();
}

__global__ void sc_setup(const int* __restrict__ info_set,
                         const float* __restrict__ E_obs,
                         const float* __restrict__ E_lab,
                         const float* __restrict__ Wb1,
                         const float* __restrict__ Wc2, const float* __restrict__ bc2,
                         const float* __restrict__ Wb2, const float* __restrict__ bb2,
                         const float* __restrict__ Wl, const float* __restrict__ bl,
                         int* __restrict__ pos2k, float* __restrict__ lab1,
                         float* __restrict__ eroot, float* __restrict__ cvb)
{
  const int t = threadIdx.x;   // 256 threads
  pos2k[t] = -1;
  __syncthreads();
  if (t < 128) pos2k[info_set[t]] = t;
  eroot[t] = E_obs[2 * 128 + (t & 127)];
  for (int j = 0; j < 2; ++j) {
    float s = 0.0f;
    for (int k = 0; k < 128; ++k)
      s = fmaf(E_lab[j * 128 + k], Wb1[(256 + k) * 256 + t], s);
    lab1[j * 256 + t] = s;
  }
  // cv[k] = Wc2[k,:]@Wl ; bv[k] = Wb2[k,:]@Wl  (k in 0..255)
  {
    float sc = 0.f, sb = 0.f;
    for (int c = 0; c < 128; ++c) {
      sc = fmaf(Wc2[t * 128 + c], Wl[c], sc);
      sb = fmaf(Wb2[t * 128 + c], Wl[c], sb);
    }
    cvb[t] = sc;
    cvb[256 + t] = sb;
  }
  if (t == 0) {
    float s = bl[0];
    for (int c = 0; c < 128; ++c) s = fmaf(bc2[c], Wl[c], s);
    cvb[512] = s;
  }
  if (t == 1) {
    float s = bl[0];
    for (int c = 0; c < 128; ++c) s = fmaf(bb2[c], Wl[c], s);
    cvb[513] = s;
  }
}

__global__ __launch_bounds__(NTHR)
__attribute__((amdgpu_waves_per_eu(4, 4)))
void sc_main(const int* __restrict__ info_bits, const float* __restrict__ rin,
             const float* __restrict__ Wc1, const float* __restrict__ bc1,
             const float* __restrict__ Wc2, const float* __restrict__ bc2,
             const float* __restrict__ Wb1, const float* __restrict__ bb1,
             const float* __restrict__ Wb2, const float* __restrict__ bb2,
             const int* __restrict__ pos2k, const float* __restrict__ lab1_g,
             const float* __restrict__ eroot_g, const float* __restrict__ cvb_g,
             float* __restrict__ wsall, float* __restrict__ out)
{
  const int b = blockIdx.x;
  const int t = threadIdx.x;
  float* e1g = wsall + (size_t)b * EG_STRIDE;      // level-1 e (global)

  __shared__ __align__(16) float red[16384];       // 64 KB split-K partials
  __shared__ __align__(16) float h_lds[3072];      // 12 KB hidden / lvl-1 z-stage
  __shared__ __align__(16) float scratch[1536];    //  6 KB: lvl-0 out UNION specs
                                                   //  spec5[0,1024) spec6[1024,1536)
  __shared__ __align__(16) float e2[8192];         // 32 KB level-2 e
  __shared__ __align__(16) float e3[4096];         // 16 KB level-3 e
  __shared__ __align__(16) float e4[2048];         //  8 KB level-4 e
  __shared__ __align__(16) float e567[1792];       // levels 5..7: 8,4,2 rows
  __shared__ __align__(16) float lab_lds[512];
  __shared__ __align__(16) float eroot[256];
  __shared__ __align__(16) float cvb_lds[516];     // cv|bv|cc|cb (+pad)
  __shared__ float rrow[256];
  __shared__ float dots[4];                        // leaf logits: check/bit0/bit1
  __shared__ int   xh[520];
  __shared__ int   ibits[128];
  __shared__ int   p2k_l[256];

  float* xO = out;
  float* fO = out + 32768;
  float* uO = out + 65536;
  float* pO = out + 98304;
  float* rO = out + 131072;

  // ---- prologue: preload constants, hoist input-independent outputs ----
  if (t < 512) lab_lds[t] = lab1_g[t];
  if (t < 514) cvb_lds[t] = cvb_g[t];
  if (t < 256) {
    eroot[t]  = eroot_g[t];
    const int k = pos2k[t];
    p2k_l[t]  = k;
    const float rv = rin[b * 256 + t];
    rrow[t]   = rv;
    rO[b * 256 + t] = rv;
    fO[b * 256 + t] = (k >= 0) ? 2.0f : 1.0f;
  }
  if (t < 128) ibits[t] = info_bits[b * 128 + t];
  if (t == 0) { xh[512] = 0; xh[513] = 1; }        // constant u1h for lvl-0 bit
  __syncthreads();

  // ---- levels 1..4: C8 chunks (R5-proven; R6's C16 regressed) ----
  auto run_level = [&](int l, bool isbit) {
    const int rows = 128 >> l;
    const float* W1 = isbit ? Wb1 : Wc1;
    const float* B1 = isbit ? bb1 : bc1;
    const float* W2 = isbit ? Wb2 : Wc2;
    const float* B2 = isbit ? bb2 : bc2;
    const int* u1h = xh + xoff(l);
    const float* ein; float* eo;
    switch (l) {
      case 1:  ein = nullptr; eo = e2;   break;
      case 2:  ein = e2;      eo = e3;   break;
      case 3:  ein = e3;      eo = e4;   break;
      default: ein = e4;      eo = e567; break;    // l == 4
    }
    for (int done = 0; done < rows; done += 8) {
      const float* zl;
      if (l == 1) {   // stage 8 z-rows into h_lds (dead until reduce1 rewrites)
        const float4* src = reinterpret_cast<const float4*>(e1g + done * 256);
        for (int i4 = t; i4 < 512; i4 += NTHR)
          reinterpret_cast<float4*>(h_lds)[i4] = src[i4];
        __syncthreads();
        zl = h_lds;
      } else {
        zl = ein + done * 256;
      }
      mlp_chunk<8>(zl, 256, W1, B1, W2, B2, lab_lds, isbit, u1h, done,
                   red, h_lds, eo + done * 128);
    }
  };

  // ---- level 0 special: check rows all identical (z = eroot); bit rows take
  // only 2 values. Compute 1 (check) or 2 (bit) rows, broadcast into e1. ----
  auto run_level0 = [&](bool isbit) {
    if (!isbit) {
      mlp_chunk<1>(eroot, 0, Wc1, bc1, Wc2, bc2, lab_lds, false, xh, 0, red, h_lds, scratch);
      for (int i4 = t; i4 < 4096; i4 += NTHR)
        reinterpret_cast<float4*>(e1g)[i4] =
            reinterpret_cast<const float4*>(scratch)[i4 & 31];
    } else {
      mlp_chunk<2>(eroot, 0, Wb1, bb1, Wb2, bb2, lab_lds, true, xh + 512, 0, red, h_lds, scratch);
      for (int i4 = t; i4 < 4096; i4 += NTHR)
        reinterpret_cast<float4*>(e1g)[i4] =
            reinterpret_cast<const float4*>(scratch)[(xh[i4 >> 5] & 1) * 32 + (i4 & 31)];
    }
    __syncthreads();
  };

  // ---- fused check+spec for l in {5,6} ----
  auto run_fused = [&](int l) {
    if (l == 5)
      fused_chunk<4>(e567, Wc1, bc1, Wc2, bc2, Wb1, bb1, Wb2, bb2, lab_lds,
                     red, h_lds, e567 + 1024, scratch);
    else
      fused_chunk<2>(e567 + 1024, Wc1, bc1, Wc2, bc2, Wb1, bb1, Wb2, bb2, lab_lds,
                     red, h_lds, e567 + 1536, scratch + 1024);
  };

  // ---- bit-time select for l in {5,6}: child e row r = spec[u1h[r]][r] ----
  auto do_select = [&](int l) {
    const int R = 128 >> l;
    const float* spec = scratch + ((l == 5) ? 0 : 1024);
    float* eo = (l == 5) ? (e567 + 1024) : (e567 + 1536);
    const int* u1h = xh + xoff(l);
    if (t < R * 128) {
      const int r = t >> 7;
      eo[t] = spec[(u1h[r] & 1) * R * 128 + t];
    }
    __syncthreads();
  };

  // ---- leaf-pair decide from precomputed logits ----
  auto do_decide = [&](int i, int s) {   // i even; s = ctz(i+2)
    if (t == 0) {
      int xv[2];
#pragma unroll
      for (int q = 0; q < 2; ++q) {
        const float dv = (q == 0) ? dots[0] : dots[1 + (xv[0] & 1)];
        const float p  = 1.0f / (1.0f + expf(-dv));
        const float rv = rrow[i + q];
        const int  hd     = (rv > p) ? 1 : 0;
        const bool frozen = fabsf(p - 0.5f) > 0.25f;
        const int  k  = p2k_l[i + q];
        const int  fc = (k >= 0) ? ibits[k] : 2;
        xv[q] = (fc == 2 || frozen) ? hd : fc;
        pO[b * 256 + i + q] = p;
        uO[b * 256 + i + q] = (float)xv[q];
      }
      const int side = (1 < s) ? 1 : 0;            // combine j=1 (level 7)
      const int base = xoff(6) + side * 2;
      xh[base]     = xv[0] ^ xv[1];
      xh[base + 1] = xv[1];
    }
    __syncthreads();
  };

  auto do_combine = [&](int l, int side) {
    const int n = 256 >> l, half = n >> 1;
    if (t < half) {
      const int u1 = xh[xoff(l) + t];
      const int u2 = xh[xoff(l) + half + t];
      if (l > 0) {
        const int base = xoff(l - 1) + side * n;
        xh[base + 2 * t]     = u1 ^ u2;
        xh[base + 2 * t + 1] = u2;
      } else {
        xO[b * 256 + 2 * t]     = (float)(u1 ^ u2);
        xO[b * 256 + 2 * t + 1] = (float)u2;
      }
    }
    __syncthreads();
  };

  // ---- SC traversal ----
  int i = 0, l = 0;
  bool isbit = false;
  while (true) {
    if (l == 7) {
      // check-visit only (bit side is covered by the spec logits)
      fused7_dot(e567 + 1536, Wc1, bc1, Wb1, bb1, lab_lds, cvb_lds,
                 red, h_lds, dots);
    } else if (l >= 5) {
      if (isbit) do_select(l);           // l is 5 or 6 here
      else       run_fused(l);
    } else if (l == 0) {
      run_level0(isbit);
    } else {
      run_level(l, isbit);
    }
    if (l < 7) { ++l; isbit = false; continue; }
    const int s = __builtin_ctz(i + 2);
    do_decide(i, s);
    if (i == 254) {
      for (int j = 2; j <= 8; ++j) do_combine(8 - j, (j < s) ? 1 : 0);
      break;
    }
    i += 2;
    for (int j = 2; j <= s; ++j) do_combine(8 - j, (j < s) ? 1 : 0);
    l = 7 - s;
    isbit = true;
  }
}

extern "C" void kernel_launch(void* const* d_in, const int* in_sizes, int n_in,
                              void* d_out, int out_size, void* d_ws, size_t ws_size,
                              hipStream_t stream)
{
  const int*   info_bits = (const int*)  d_in[0];
  const float* rin       = (const float*)d_in[1];
  const int*   info_set  = (const int*)  d_in[2];
  const float* E_obs     = (const float*)d_in[3];
  const float* E_lab     = (const float*)d_in[4];
  const float* Wc1 = (const float*)d_in[5];
  const float* bc1 = (const float*)d_in[6];
  const float* Wc2 = (const float*)d_in[7];
  const float* bc2 = (const float*)d_in[8];
  const float* Wb1 = (const float*)d_in[9];
  const float* bb1 = (const float*)d_in[10];
  const float* Wb2 = (const float*)d_in[11];
  const float* bb2 = (const float*)d_in[12];
  const float* Wl  = (const float*)d_in[13];
  const float* bl  = (const float*)d_in[14];

  int*   pos2k = (int*)d_ws;                 // [0,256) ints
  float* lab1  = (float*)d_ws + 256;         // [256,768)
  float* eroot = (float*)d_ws + 768;         // [768,1024)
  float* cvb   = (float*)d_ws + 1024;        // [1024,1538): cv|bv|cc|cb
  float* wsall = (float*)d_ws + 2048;        // 128 x EG_STRIDE floats

  hipLaunchKernelGGL(sc_setup, dim3(1), dim3(256), 0, stream,
                     info_set, E_obs, E_lab, Wb1, Wc2, bc2, Wb2, bb2,
                     (const float*)d_in[13], (const float*)d_in[14],
                     pos2k, lab1, eroot, cvb);
  hipLaunchKernelGGL(sc_main, dim3(128), dim3(NTHR), 0, stream,
                     info_bits, rin,
                     Wc1, bc1, Wc2, bc2, Wb1, bb1, Wb2, bb2,
                     pos2k, lab1, eroot, cvb, wsall, (float*)d_out);
}